// Round 3
// baseline (405.541 us; speedup 1.0000x reference)
//
#include <hip/hip_runtime.h>
#include <math.h>

// Problem constants
#define NPX   1048576      // 1024*1024
#define TD    1025         // tex_eval spatial dim
#define PW    35           // patch width (cells) for 32-wide tile
#define PH    11           // patch height (cells) for 8-tall tile (6 blocks/CU)
#define DPAD  1028         // padded input spatial dim (rows -2..1025 -> 0..1027)
#define ROWB  65792        // DPAD*32*2 bytes per padded row
// ws layout: [0, 16KB)            ffrag_g fp16 [kk][lane][8] (MFMA frag order)
//            [48KB, +33.62MB)     tex     fp16 [y][x][c]  (TD*TD*16)
//            [DP_OFF, +67.63MB)   Dp      fp16 [1028][1028][32] zero-padded CL
#define DP_OFF 33673216

typedef _Float16 half8 __attribute__((ext_vector_type(8)));
typedef _Float16 half4 __attribute__((ext_vector_type(4)));
typedef float    f32x4 __attribute__((ext_vector_type(4)));

__device__ __forceinline__ void load_lds16(const void* g, void* lds) {
    __builtin_amdgcn_global_load_lds(
        (const __attribute__((address_space(1))) void*)g,
        (__attribute__((address_space(3))) void*)lds, 16, 0, 0);
}

// ------- Stage 1: MLP -> MFMA fragment-ordered fp16 filter (fused) -----------
// Each of 32 blocks redundantly computes layers 1-2 (tiny), then its 256
// layer-3 outputs, writing each tanh directly into MFMA fragment order:
// ffrag_g[(kk*64 + (ic>>3)*16 + oc)*8 + (ic&7)],  o = oc*512 + ic*16 + kk.
__global__ __launch_bounds__(256) void mlp_kernel(
    const float* __restrict__ expr,
    const float* __restrict__ W1, const float* __restrict__ b1,
    const float* __restrict__ W2, const float* __restrict__ b2,
    const float* __restrict__ W3, const float* __restrict__ b3,
    _Float16* __restrict__ ffrag_g)
{
    __shared__ float sx[76];
    __shared__ float sh1[128];
    __shared__ float sh2[64];
    int t = threadIdx.x;
    if (t < 76) sx[t] = expr[t];
    __syncthreads();
    if (t < 128) {
        float a = b1[t];
        const float* w = W1 + t * 76;
        #pragma unroll 4
        for (int i = 0; i < 76; ++i) a += sx[i] * w[i];
        sh1[t] = a >= 0.f ? a : 0.02f * a;
    }
    __syncthreads();
    if (t < 64) {
        float a = b2[t];
        const float* w = W2 + t * 128;
        #pragma unroll 4
        for (int i = 0; i < 128; ++i) a += sh1[i] * w[i];
        sh2[t] = a >= 0.f ? a : 0.02f * a;
    }
    __syncthreads();
    int o = blockIdx.x * 256 + t;            // 0..8191
    float a = b3[o];
    const float* w = W3 + o * 64;
    #pragma unroll 4
    for (int i = 0; i < 64; ++i) a += sh2[i] * w[i];
    a = tanhf(a);
    int oc = o >> 9;                          // o / 512
    int ic = (o >> 4) & 31;
    int kk = o & 15;                          // ky*4+kx
    ffrag_g[(size_t)(kk * 64 + (ic >> 3) * 16 + oc) * 8 + (ic & 7)] = (_Float16)a;
}

// ------ Stage 1c: repack data fp32 NCHW -> zero-padded fp16 channel-last -----
// Dp[Y][X][ic], Y = y+2, X = x+2, zeros outside [0,1024). Fully coalesced via
// XOR-swizzled LDS transpose (conflict-free writes AND reads).
__global__ __launch_bounds__(256) void repack_kernel(
    const float* __restrict__ data, _Float16* __restrict__ Dp)
{
    __shared__ _Float16 s[256 * 32];          // 16 KB
    int tid = threadIdx.x;
    int Y = blockIdx.y;
    int X = blockIdx.x * 256 + tid;
    int y = Y - 2, x = X - 2;
    bool ok = ((unsigned)y < 1024u) && ((unsigned)x < 1024u);
    const float* dp = data + ((size_t)y << 10) + x;

    float v[32];
    #pragma unroll
    for (int j = 0; j < 32; ++j) v[j] = 0.f;
    if (ok) {
        #pragma unroll
        for (int j = 0; j < 32; ++j) v[j] = __builtin_nontemporal_load(&dp[(size_t)j * NPX]);
    }
    #pragma unroll
    for (int g = 0; g < 4; ++g) {
        half8 h;
        #pragma unroll
        for (int j = 0; j < 8; ++j) h[j] = (_Float16)v[g * 8 + j];
        int chunk = tid * 4 + g;
        int sw = chunk ^ ((chunk >> 3) & 7);  // spread banks
        *(half8*)((char*)s + sw * 16) = h;
    }
    __syncthreads();
    char* rowbase = (char*)Dp + (size_t)Y * ROWB + blockIdx.x * 16384;
    int lim = ROWB - blockIdx.x * 16384;
    #pragma unroll
    for (int i = 0; i < 4; ++i) {
        int off = tid * 16 + i * 4096;
        if (off < lim) {
            int chunk = tid + i * 256;
            int sw = chunk ^ ((chunk >> 3) & 7);
            *(uint4*)(rowbase + off) = *(uint4*)((char*)s + sw * 16);
        }
    }
}

// ------------- Stage 2: implicit-GEMM conv via 16x16x32 f16 MFMA -------------
// Tile 32(x) x 8(y): LDS 24,640 B -> 6 blocks/CU (R2's proven occupancy win).
// R3 reverts the tex2 duplicated-pair layout (R2 post-mortem: its epilogue
// covered only 32 B of every 64-B line PER INSTRUCTION -> TCC partial-sector
// RMW, 5x write amp, 346 MB writes). Back to single tex + the R1 epilogue,
// whose wave store covers 512 CONTIGUOUS bytes per instruction.
__global__ __launch_bounds__(256, 6) void conv_mfma_kernel(
    const _Float16* __restrict__ Dp,         // [1028][1028][32] fp16
    const _Float16* __restrict__ ffrag_g,    // [16][64][8] fp16
    _Float16* __restrict__ tex)              // [1025][1025][16] fp16
{
    __shared__ __attribute__((aligned(128))) _Float16 sp[PH * PW * 32]; // 24,640 B

    int tid = threadIdx.x;
    int l = tid & 63, w = tid >> 6;
    int ox0 = blockIdx.x * 32;
    int oy0 = blockIdx.y * 8;

    // filter fragments -> registers, L2-hot
    half8 bfrag[16];
    #pragma unroll
    for (int kk = 0; kk < 16; ++kk)
        bfrag[kk] = *(const half8*)&ffrag_g[kk * 512 + l * 8];

    // stage patch rows; LDS dest linear, chunk swizzle realized on the GLOBAL
    // source address (involution, rule 21). Edge tiles clamp source only.
    int lsw = l ^ ((l >> 3) & 7);            // source-chunk permutation
    for (int r = w; r < PH; r += 4) {
        int gy = min(oy0 + r, DPAD - 1);
        const char* grow = (const char*)Dp + (size_t)gy * ROWB;
        _Float16* lrow = sp + r * (PW * 32);
        #pragma unroll
        for (int c = 0; c < 3; ++c) {
            int off = ox0 * 64 + c * 1024 + lsw * 16;
            off = min(off, ROWB - 16);
            if (c < 2 || l < 12)             // lsw maps 0..11 -> 0..11
                load_lds16(grow + off, (char*)lrow + c * 1024);
        }
    }
    __syncthreads();

    int lane15 = l & 15;
    int q = l >> 4;

    // Swizzled A-frag byte offsets: logical chunk in row = (t&1)*64 + kx*4 + u;
    // the (t&1)*64 term commutes with the XOR (bit 6 untouched).
    int u = lane15 * 4 + q;
    int sv[4];
    #pragma unroll
    for (int kx = 0; kx < 4; ++kx) {
        int vch = kx * 4 + u;
        sv[kx] = (vch ^ ((vch >> 3) & 7)) * 16;    // byte offset in row
    }

    f32x4 acc[4];
    #pragma unroll
    for (int t = 0; t < 4; ++t) acc[t] = (f32x4){0.f, 0.f, 0.f, 0.f};

    // m-tile t: tile row (w*2 + (t>>1)), x half (t&1); lane pixel = lane15
    #pragma unroll 4
    for (int kk = 0; kk < 16; ++kk) {
        int ky = kk >> 2, kx = kk & 3;
        #pragma unroll
        for (int t = 0; t < 4; ++t) {
            const char* ap = (const char*)sp
                + (w * 2 + (t >> 1) + ky) * (PW * 64)  // row * 2240 B
                + (t & 1) * 1024 + sv[kx];
            half8 af = *(const half8*)ap;
            // swapped operands: D col = lane&15 = pixel, row = q*4+reg = channel
            acc[t] = __builtin_amdgcn_mfma_f32_16x16x32_f16(bfrag[kk], af, acc[t], 0, 0, 0);
        }
    }

    // epilogue: lane holds channels q*4..q*4+3 of pixel px. One 8-B packed
    // store per tile; wave covers [px0*32, px0*32+512) fully contiguous.
    #pragma unroll
    for (int t = 0; t < 4; ++t) {
        int oy = oy0 + w * 2 + (t >> 1);
        int px = ox0 + (t & 1) * 16 + lane15;
        if (oy > 1024 || px > 1024) continue;
        half4 hv;
        #pragma unroll
        for (int r = 0; r < 4; ++r) hv[r] = (_Float16)acc[t][r];
        *(half4*)&tex[((size_t)oy * TD + px) * 16 + q * 4] = hv;
    }
}

// ---------------- Stage 3: bilinear grid-sample (border pad) -----------------
// 2 px/thread: 16 independent texel loads in flight per wave (vs 8) to hide
// L3 gather latency on the 33.6-MB L3-resident texture. All loads issued
// before any use; nontemporal uv/out (stream-once).
__global__ __launch_bounds__(256, 4) void sample_kernel(
    const float* __restrict__ uv,            // [2][1024][1024]
    const _Float16* __restrict__ tex,        // [1025][1025][16] fp16
    float* __restrict__ out)                 // [16][1024][1024]
{
    int pa = blockIdx.x * 512 + threadIdx.x; // pixel A
    int pb = pa + 256;                       // pixel B

    float xa = __builtin_nontemporal_load(&uv[pa]);
    float ya = __builtin_nontemporal_load(&uv[NPX + pa]);
    float xb = __builtin_nontemporal_load(&uv[pb]);
    float yb = __builtin_nontemporal_load(&uv[NPX + pb]);

    float ixa = fminf(fmaxf(((xa + 1.f) * 1025.f - 1.f) * 0.5f, 0.f), 1024.f);
    float iya = fminf(fmaxf(((ya + 1.f) * 1025.f - 1.f) * 0.5f, 0.f), 1024.f);
    float ixb = fminf(fmaxf(((xb + 1.f) * 1025.f - 1.f) * 0.5f, 0.f), 1024.f);
    float iyb = fminf(fmaxf(((yb + 1.f) * 1025.f - 1.f) * 0.5f, 0.f), 1024.f);

    float fxa = floorf(ixa), fya = floorf(iya);
    float fxb = floorf(ixb), fyb = floorf(iyb);
    float wxa = ixa - fxa, wya = iya - fya;
    float wxb = ixb - fxb, wyb = iyb - fyb;
    int x0a = (int)fxa, y0a = (int)fya;
    int x0b = (int)fxb, y0b = (int)fyb;
    int x1a = min(x0a + 1, 1024), y1a = min(y0a + 1, 1024);
    int x1b = min(x0b + 1, 1024), y1b = min(y0b + 1, 1024);

    const half8* a00 = (const half8*)(tex + ((size_t)y0a * TD + x0a) * 16);
    const half8* a01 = (const half8*)(tex + ((size_t)y0a * TD + x1a) * 16);
    const half8* a10 = (const half8*)(tex + ((size_t)y1a * TD + x0a) * 16);
    const half8* a11 = (const half8*)(tex + ((size_t)y1a * TD + x1a) * 16);
    const half8* b00 = (const half8*)(tex + ((size_t)y0b * TD + x0b) * 16);
    const half8* b01 = (const half8*)(tex + ((size_t)y0b * TD + x1b) * 16);
    const half8* b10 = (const half8*)(tex + ((size_t)y1b * TD + x0b) * 16);
    const half8* b11 = (const half8*)(tex + ((size_t)y1b * TD + x1b) * 16);

    half8 va0 = a00[0], va1 = a00[1];
    half8 va2 = a01[0], va3 = a01[1];
    half8 va4 = a10[0], va5 = a10[1];
    half8 va6 = a11[0], va7 = a11[1];
    half8 vb0 = b00[0], vb1 = b00[1];
    half8 vb2 = b01[0], vb3 = b01[1];
    half8 vb4 = b10[0], vb5 = b10[1];
    half8 vb6 = b11[0], vb7 = b11[1];

    float wa00 = (1.f - wxa) * (1.f - wya);
    float wa01 = wxa * (1.f - wya);
    float wa10 = (1.f - wxa) * wya;
    float wa11 = wxa * wya;
    float wb00 = (1.f - wxb) * (1.f - wyb);
    float wb01 = wxb * (1.f - wyb);
    float wb10 = (1.f - wxb) * wyb;
    float wb11 = wxb * wyb;

    #pragma unroll
    for (int c = 0; c < 8; ++c) {
        float ra0 = (float)va0[c] * wa00 + (float)va2[c] * wa01
                  + (float)va4[c] * wa10 + (float)va6[c] * wa11;
        float ra1 = (float)va1[c] * wa00 + (float)va3[c] * wa01
                  + (float)va5[c] * wa10 + (float)va7[c] * wa11;
        float rb0 = (float)vb0[c] * wb00 + (float)vb2[c] * wb01
                  + (float)vb4[c] * wb10 + (float)vb6[c] * wb11;
        float rb1 = (float)vb1[c] * wb00 + (float)vb3[c] * wb01
                  + (float)vb5[c] * wb10 + (float)vb7[c] * wb11;
        __builtin_nontemporal_store(ra0, &out[(size_t)c * NPX + pa]);
        __builtin_nontemporal_store(ra1, &out[(size_t)(c + 8) * NPX + pa]);
        __builtin_nontemporal_store(rb0, &out[(size_t)c * NPX + pb]);
        __builtin_nontemporal_store(rb1, &out[(size_t)(c + 8) * NPX + pb]);
    }
}

extern "C" void kernel_launch(void* const* d_in, const int* in_sizes, int n_in,
                              void* d_out, int out_size, void* d_ws, size_t ws_size,
                              hipStream_t stream) {
    const float* expr = (const float*)d_in[0];
    // d_in[1] = audio_features: unused by the reference
    const float* uv   = (const float*)d_in[2];
    const float* data = (const float*)d_in[3];
    const float* W1   = (const float*)d_in[4];
    const float* b1   = (const float*)d_in[5];
    const float* W2   = (const float*)d_in[6];
    const float* b2   = (const float*)d_in[7];
    const float* W3   = (const float*)d_in[8];
    const float* b3   = (const float*)d_in[9];
    float* out = (float*)d_out;

    _Float16* ffrag_g  = (_Float16*)d_ws;                            // 16 KB
    _Float16* tex      = (_Float16*)((char*)d_ws + 49152);           // 33.62 MB
    _Float16* Dp       = (_Float16*)((char*)d_ws + DP_OFF);          // 67.63 MB

    mlp_kernel<<<32, 256, 0, stream>>>(expr, W1, b1, W2, b2, W3, b3, ffrag_g);
    repack_kernel<<<dim3(5, DPAD), 256, 0, stream>>>(data, Dp);
    conv_mfma_kernel<<<dim3(33, 129), 256, 0, stream>>>(Dp, ffrag_g, tex);
    sample_kernel<<<NPX / 512, 256, 0, stream>>>(uv, tex, out);
}

// Round 5
// 326.460 us; speedup vs baseline: 1.2422x; 1.2422x over previous
//
#include <hip/hip_runtime.h>
#include <math.h>

// Problem constants
#define NPX   1048576      // 1024*1024
#define TD    1025         // tex_eval spatial dim
#define PW    35           // patch width (cells) for 32-wide tile
#define PH    11           // patch height (cells) for 8-tall tile
#define DPAD  1028         // padded input spatial dim (rows -2..1025 -> 0..1027)
#define ROWB  65792        // DPAD*32*2 bytes per padded row
// ws layout: [0, 16KB)            ffrag_g fp16 [kk][lane][8] (MFMA frag order)
//            [48KB, +33.62MB)     tex     fp16 [y][x][c]  (TD*TD*16)
//            [DP_OFF, +67.63MB)   Dp      fp16 [1028][1028][32] zero-padded CL
#define DP_OFF 33673216

typedef _Float16 half8 __attribute__((ext_vector_type(8)));
typedef _Float16 half4 __attribute__((ext_vector_type(4)));
typedef float    f32x4 __attribute__((ext_vector_type(4)));

__device__ __forceinline__ void load_lds16(const void* g, void* lds) {
    __builtin_amdgcn_global_load_lds(
        (const __attribute__((address_space(1))) void*)g,
        (__attribute__((address_space(3))) void*)lds, 16, 0, 0);
}

// ------- Stage 1: MLP -> MFMA fragment-ordered fp16 filter (fused) -----------
__global__ __launch_bounds__(256) void mlp_kernel(
    const float* __restrict__ expr,
    const float* __restrict__ W1, const float* __restrict__ b1,
    const float* __restrict__ W2, const float* __restrict__ b2,
    const float* __restrict__ W3, const float* __restrict__ b3,
    _Float16* __restrict__ ffrag_g)
{
    __shared__ float sx[76];
    __shared__ float sh1[128];
    __shared__ float sh2[64];
    int t = threadIdx.x;
    if (t < 76) sx[t] = expr[t];
    __syncthreads();
    if (t < 128) {
        float a = b1[t];
        const float* w = W1 + t * 76;
        #pragma unroll 4
        for (int i = 0; i < 76; ++i) a += sx[i] * w[i];
        sh1[t] = a >= 0.f ? a : 0.02f * a;
    }
    __syncthreads();
    if (t < 64) {
        float a = b2[t];
        const float* w = W2 + t * 128;
        #pragma unroll 4
        for (int i = 0; i < 128; ++i) a += sh1[i] * w[i];
        sh2[t] = a >= 0.f ? a : 0.02f * a;
    }
    __syncthreads();
    int o = blockIdx.x * 256 + t;            // 0..8191
    float a = b3[o];
    const float* w = W3 + o * 64;
    #pragma unroll 4
    for (int i = 0; i < 64; ++i) a += sh2[i] * w[i];
    a = tanhf(a);
    int oc = o >> 9;                          // o / 512
    int ic = (o >> 4) & 31;
    int kk = o & 15;                          // ky*4+kx
    ffrag_g[(size_t)(kk * 64 + (ic >> 3) * 16 + oc) * 8 + (ic & 7)] = (_Float16)a;
}

// ------ Stage 1c: repack data fp32 NCHW -> zero-padded fp16 channel-last -----
__global__ __launch_bounds__(256) void repack_kernel(
    const float* __restrict__ data, _Float16* __restrict__ Dp)
{
    __shared__ _Float16 s[256 * 32];          // 16 KB
    int tid = threadIdx.x;
    int Y = blockIdx.y;
    int X = blockIdx.x * 256 + tid;
    int y = Y - 2, x = X - 2;
    bool ok = ((unsigned)y < 1024u) && ((unsigned)x < 1024u);
    const float* dp = data + ((size_t)y << 10) + x;

    float v[32];
    #pragma unroll
    for (int j = 0; j < 32; ++j) v[j] = 0.f;
    if (ok) {
        #pragma unroll
        for (int j = 0; j < 32; ++j) v[j] = __builtin_nontemporal_load(&dp[(size_t)j * NPX]);
    }
    #pragma unroll
    for (int g = 0; g < 4; ++g) {
        half8 h;
        #pragma unroll
        for (int j = 0; j < 8; ++j) h[j] = (_Float16)v[g * 8 + j];
        int chunk = tid * 4 + g;
        int sw = chunk ^ ((chunk >> 3) & 7);  // spread banks
        *(half8*)((char*)s + sw * 16) = h;
    }
    __syncthreads();
    char* rowbase = (char*)Dp + (size_t)Y * ROWB + blockIdx.x * 16384;
    int lim = ROWB - blockIdx.x * 16384;
    #pragma unroll
    for (int i = 0; i < 4; ++i) {
        int off = tid * 16 + i * 4096;
        if (off < lim) {
            int chunk = tid + i * 256;
            int sw = chunk ^ ((chunk >> 3) & 7);
            *(uint4*)(rowbase + off) = *(uint4*)((char*)s + sw * 16);
        }
    }
}

// ------------- Stage 2: implicit-GEMM conv via 16x16x32 f16 MFMA -------------
// Rule-#20 fix: the kk loop was `#pragma unroll 4`, leaving kk RUNTIME inside
// each unrolled body -> bfrag[kk] runtime-indexed -> the whole 256 B/thread
// array lived in SCRATCH since R0 (64 KB/block write + re-read = the exact
// 272 MB write / +80 MB fetch anomaly; VGPR_Count=40 confirmed). Fix: FULL
// unroll (all bfrag indices compile-time) + launch_bounds(256,4) (128-VGPR
// budget; (256,6)'s ~85-VGPR cap is what forced the demotion).
__global__ __launch_bounds__(256, 4) void conv_mfma_kernel(
    const _Float16* __restrict__ Dp,         // [1028][1028][32] fp16
    const _Float16* __restrict__ ffrag_g,    // [16][64][8] fp16
    _Float16* __restrict__ tex)              // [1025][1025][16] fp16
{
    __shared__ __attribute__((aligned(128))) _Float16 sp[PH * PW * 32]; // 24,640 B

    int tid = threadIdx.x;
    int l = tid & 63, w = tid >> 6;
    int ox0 = blockIdx.x * 32;
    int oy0 = blockIdx.y * 8;

    // filter fragments -> registers (64 VGPR), L2-hot
    half8 bfrag[16];
    #pragma unroll
    for (int kk = 0; kk < 16; ++kk)
        bfrag[kk] = *(const half8*)&ffrag_g[kk * 512 + l * 8];

    // stage patch rows; LDS dest linear, chunk swizzle realized on the GLOBAL
    // source address (involution, rule 21). Edge tiles clamp source only.
    int lsw = l ^ ((l >> 3) & 7);            // source-chunk permutation
    for (int r = w; r < PH; r += 4) {
        int gy = min(oy0 + r, DPAD - 1);
        const char* grow = (const char*)Dp + (size_t)gy * ROWB;
        _Float16* lrow = sp + r * (PW * 32);
        #pragma unroll
        for (int c = 0; c < 3; ++c) {
            int off = ox0 * 64 + c * 1024 + lsw * 16;
            off = min(off, ROWB - 16);
            if (c < 2 || l < 12)             // lsw maps 0..11 -> 0..11
                load_lds16(grow + off, (char*)lrow + c * 1024);
        }
    }
    __syncthreads();

    int lane15 = l & 15;
    int q = l >> 4;

    // Swizzled A-frag byte offsets: logical chunk in row = (t&1)*64 + kx*4 + u;
    // the (t&1)*64 term commutes with the XOR (bit 6 untouched).
    int u = lane15 * 4 + q;
    int sv[4];
    #pragma unroll
    for (int kx = 0; kx < 4; ++kx) {
        int vch = kx * 4 + u;
        sv[kx] = (vch ^ ((vch >> 3) & 7)) * 16;    // byte offset in row
    }

    f32x4 acc[4];
    #pragma unroll
    for (int t = 0; t < 4; ++t) acc[t] = (f32x4){0.f, 0.f, 0.f, 0.f};

    // m-tile t: tile row (w*2 + (t>>1)), x half (t&1); lane pixel = lane15
    // FULL unroll: every bfrag/sv/acc index is a compile-time constant.
    #pragma unroll
    for (int kk = 0; kk < 16; ++kk) {
        int ky = kk >> 2, kx = kk & 3;
        #pragma unroll
        for (int t = 0; t < 4; ++t) {
            const char* ap = (const char*)sp
                + (w * 2 + (t >> 1) + ky) * (PW * 64)  // row * 2240 B
                + (t & 1) * 1024 + sv[kx];
            half8 af = *(const half8*)ap;
            // swapped operands: D col = lane&15 = pixel, row = q*4+reg = channel
            acc[t] = __builtin_amdgcn_mfma_f32_16x16x32_f16(bfrag[kk], af, acc[t], 0, 0, 0);
        }
    }

    // epilogue: lane holds channels q*4..q*4+3 of pixel px. One 8-B packed
    // store per tile; wave covers 512 contiguous bytes per instruction.
    #pragma unroll
    for (int t = 0; t < 4; ++t) {
        int oy = oy0 + w * 2 + (t >> 1);
        int px = ox0 + (t & 1) * 16 + lane15;
        if (oy > 1024 || px > 1024) continue;
        half4 hv;
        #pragma unroll
        for (int r = 0; r < 4; ++r) hv[r] = (_Float16)acc[t][r];
        *(half4*)&tex[((size_t)oy * TD + px) * 16 + q * 4] = hv;
    }
}

// ---------------- Stage 3: bilinear grid-sample (border pad) -----------------
// 1 px/thread, max occupancy (accounting across R1-R3: the 2-px/thread ILP
// variant cost ~+10-17 us vs this form).
__global__ __launch_bounds__(256, 6) void sample_kernel(
    const float* __restrict__ uv,            // [2][1024][1024]
    const _Float16* __restrict__ tex,        // [1025][1025][16] fp16
    float* __restrict__ out)                 // [16][1024][1024]
{
    int p = blockIdx.x * 256 + threadIdx.x;  // 0..NPX-1
    float x = __builtin_nontemporal_load(&uv[p]);
    float y = __builtin_nontemporal_load(&uv[NPX + p]);
    float ix = fminf(fmaxf(((x + 1.f) * 1025.f - 1.f) * 0.5f, 0.f), 1024.f);
    float iy = fminf(fmaxf(((y + 1.f) * 1025.f - 1.f) * 0.5f, 0.f), 1024.f);
    float fx0 = floorf(ix), fy0 = floorf(iy);
    float wx = ix - fx0, wy = iy - fy0;
    int x0 = (int)fx0, y0 = (int)fy0;
    int x1 = min(x0 + 1, 1024), y1 = min(y0 + 1, 1024);

    const half8* t00 = (const half8*)(tex + ((size_t)y0 * TD + x0) * 16);
    const half8* t01 = (const half8*)(tex + ((size_t)y0 * TD + x1) * 16);
    const half8* t10 = (const half8*)(tex + ((size_t)y1 * TD + x0) * 16);
    const half8* t11 = (const half8*)(tex + ((size_t)y1 * TD + x1) * 16);

    half8 v0 = t00[0], v1 = t00[1];
    half8 v2 = t01[0], v3 = t01[1];
    half8 v4 = t10[0], v5 = t10[1];
    half8 v6 = t11[0], v7 = t11[1];

    float w00 = (1.f - wx) * (1.f - wy);
    float w01 = wx * (1.f - wy);
    float w10 = (1.f - wx) * wy;
    float w11 = wx * wy;

    #pragma unroll
    for (int c = 0; c < 8; ++c) {
        float r0 = (float)v0[c] * w00 + (float)v2[c] * w01
                 + (float)v4[c] * w10 + (float)v6[c] * w11;
        float r1 = (float)v1[c] * w00 + (float)v3[c] * w01
                 + (float)v5[c] * w10 + (float)v7[c] * w11;
        __builtin_nontemporal_store(r0, &out[(size_t)c * NPX + p]);
        __builtin_nontemporal_store(r1, &out[(size_t)(c + 8) * NPX + p]);
    }
}

extern "C" void kernel_launch(void* const* d_in, const int* in_sizes, int n_in,
                              void* d_out, int out_size, void* d_ws, size_t ws_size,
                              hipStream_t stream) {
    const float* expr = (const float*)d_in[0];
    // d_in[1] = audio_features: unused by the reference
    const float* uv   = (const float*)d_in[2];
    const float* data = (const float*)d_in[3];
    const float* W1   = (const float*)d_in[4];
    const float* b1   = (const float*)d_in[5];
    const float* W2   = (const float*)d_in[6];
    const float* b2   = (const float*)d_in[7];
    const float* W3   = (const float*)d_in[8];
    const float* b3   = (const float*)d_in[9];
    float* out = (float*)d_out;

    _Float16* ffrag_g  = (_Float16*)d_ws;                            // 16 KB
    _Float16* tex      = (_Float16*)((char*)d_ws + 49152);           // 33.62 MB
    _Float16* Dp       = (_Float16*)((char*)d_ws + DP_OFF);          // 67.63 MB

    mlp_kernel<<<32, 256, 0, stream>>>(expr, W1, b1, W2, b2, W3, b3, ffrag_g);
    repack_kernel<<<dim3(5, DPAD), 256, 0, stream>>>(data, Dp);
    conv_mfma_kernel<<<dim3(33, 129), 256, 0, stream>>>(Dp, ffrag_g, tex);
    sample_kernel<<<NPX / 256, 256, 0, stream>>>(uv, tex, out);
}